// Round 7
// baseline (851.751 us; speedup 1.0000x reference)
//
#include <hip/hip_runtime.h>
#include <stdint.h>
#include <stddef.h>

typedef __attribute__((ext_vector_type(4))) float f32x4;
typedef __attribute__((ext_vector_type(4))) int   i32x4;

constexpr int B = 4, P = 48000, C = 64, NY = 496, NX = 432, CMAP = 16;
constexpr int CT  = C + CMAP;            // 80 output channels
constexpr int X4  = NX / 4;              // 108 float4 groups per full row
constexpr int CQ  = C / 4;               // 16 channel quads
constexpr int XH  = NX / 2;              // 216: half-row for map LDS tile
constexpr int XH4 = XH / 4;              // 54
constexpr size_t PL = (size_t)NY * NX;   // 214,272 channel-plane stride
constexpr size_t OUT_FLOATS = (size_t)B * CT * PL;      // 68,567,040
constexpr size_t OUT_BYTES  = OUT_FLOATS * 4;           // 274,268,160

// Pass A: build inverse map cell -> point id (cells unique by construction)
__global__ void scatter_inv_kernel(const int* __restrict__ coords,
                                   int* __restrict__ inv) {
    int p = blockIdx.x * blockDim.x + threadIdx.x;
    if (p >= P) return;
    const int4 cd = ((const int4*)coords)[p];     // (b, 0, y, x)
    inv[(cd.x * NY + cd.z) * NX + cd.w] = p;
}

// ---------------- PROBES (write only to ws canvas region) ----------------
// Honest vox-store probe: exact plane-strided pattern, cq ROTATED per pass
// so every (thread,pass) address is unique — no L2 dirty-hit, no store-sink.
// 10 passes x 219 MB = 2.19 GB of pattern-true NT stores.
__global__ void __launch_bounds__(256) probe_vox_store_kernel(
        float* __restrict__ ws) {
    const int x4 = threadIdx.x & 127;
    if (x4 >= X4) return;
    const int y   = (blockIdx.y << 1) | (threadIdx.x >> 7);
    const int bcq = blockIdx.z;
    const int cq0 = bcq & (CQ - 1);
    const int b   = bcq >> 4;
    const size_t rowoff = (size_t)y * NX + x4 * 4;
    #pragma unroll 1
    for (int pass = 0; pass < 10; ++pass) {
        const int cq = (cq0 + pass) & (CQ - 1);     // rotate target planes
        float* ob = ws + ((size_t)b * CT + cq * 4) * PL + rowoff;
        f32x4 s; s.x = s.y = s.z = s.w = (float)pass;
        __builtin_nontemporal_store(s, (f32x4*)(ob));
        __builtin_nontemporal_store(s, (f32x4*)(ob + PL));
        __builtin_nontemporal_store(s, (f32x4*)(ob + 2 * PL));
        __builtin_nontemporal_store(s, (f32x4*)(ob + 3 * PL));
    }
}

// Honest map-read probe: exact map-transpose read pattern (64B chunks at
// ~31KB stride), y-pair rotated per pass (37 coprime to 248) so loads are
// pass-dependent and cannot be hoisted. 20 passes x 110 MB = 2.2 GB reads.
// Accumulator dumped to ws defeats DCE.
__global__ void __launch_bounds__(256) probe_map_read_kernel(
        const float* __restrict__ map, float* __restrict__ ws) {
    const int tid  = threadIdx.x;
    const int half = blockIdx.x;
    const int b    = blockIdx.z;
    const int x0   = half * XH;
    const f32x4* map4 = (const f32x4*)map;
    f32x4 acc = (f32x4)0.f;
    #pragma unroll 1
    for (int pass = 0; pass < 20; ++pass) {
        int yp = blockIdx.y + pass * 37;
        yp -= (yp >= 248) ? 248 : 0;
        yp -= (yp >= 248) ? 248 : 0;
        yp -= (yp >= 248) ? 248 : 0;                 // yp mod 248 (pass*37<1295)
        const int y0 = yp << 1;
        #pragma unroll
        for (int k = 0; k < 7; ++k) {
            int idx = k * 256 + tid;
            if (idx < XH * 8) {
                int xh = idx >> 3, r = idx & 7, yy = r >> 2, q = r & 3;
                f32x4 mv = map4[((size_t)(b * NX + x0 + xh) * NY + y0 + yy) * 4 + q];
                acc.x += mv.x; acc.y += mv.y; acc.z += mv.z; acc.w += mv.w;
            }
        }
    }
    // one 16B dump per thread (2048 blocks x 256 thr -> fits canvas region)
    size_t g = ((size_t)((blockIdx.z * 248 + blockIdx.y) * 2 + blockIdx.x)) * 256 + tid;
    ((f32x4*)ws)[g] = acc;
}

// ---------------- real kernels (r5 structure, unchanged) ----------------
__global__ void __launch_bounds__(256) vox_fill_kernel(
        const float* __restrict__ vox, const int* __restrict__ inv,
        float* __restrict__ out) {
    const int x4  = threadIdx.x & 127;
    if (x4 >= X4) return;
    const int y   = (blockIdx.y << 1) | (threadIdx.x >> 7);
    const int bcq = blockIdx.z;
    const int cq  = bcq & (CQ - 1);
    const int b   = bcq >> 4;
    const int c0  = cq * 4;

    i32x4 p4 = ((const i32x4*)inv)[(b * NY + y) * X4 + x4];

    f32x4 r0 = (f32x4)0.f, r1 = (f32x4)0.f, r2 = (f32x4)0.f, r3 = (f32x4)0.f;
    if ((p4.x & p4.y & p4.z & p4.w) >= 0) {
        const f32x4* vox4 = (const f32x4*)vox;
        if (p4.x >= 0) r0 = vox4[(size_t)p4.x * CQ + cq];
        if (p4.y >= 0) r1 = vox4[(size_t)p4.y * CQ + cq];
        if (p4.z >= 0) r2 = vox4[(size_t)p4.z * CQ + cq];
        if (p4.w >= 0) r3 = vox4[(size_t)p4.w * CQ + cq];
    }

    float* ob = out + (((size_t)b * CT + c0) * NY + y) * NX + x4 * 4;
    f32x4 s;
    s.x = r0.x; s.y = r1.x; s.z = r2.x; s.w = r3.x;
    __builtin_nontemporal_store(s, (f32x4*)(ob));
    s.x = r0.y; s.y = r1.y; s.z = r2.y; s.w = r3.y;
    __builtin_nontemporal_store(s, (f32x4*)(ob + PL));
    s.x = r0.z; s.y = r1.z; s.z = r2.z; s.w = r3.z;
    __builtin_nontemporal_store(s, (f32x4*)(ob + 2 * PL));
    s.x = r0.w; s.y = r1.w; s.z = r2.w; s.w = r3.w;
    __builtin_nontemporal_store(s, (f32x4*)(ob + 3 * PL));
}

__global__ void __launch_bounds__(256) map_tile_kernel(
        const float* __restrict__ map, float* __restrict__ out) {
    __shared__ __align__(16) float m_s[2][CMAP][XH + 4];

    const int tid  = threadIdx.x;
    const int half = blockIdx.x;
    const int y0   = blockIdx.y << 1;
    const int b    = blockIdx.z;
    const int x0   = half * XH;

    const f32x4* map4 = (const f32x4*)map;
    #pragma unroll
    for (int k = 0; k < 7; ++k) {
        int idx = k * 256 + tid;
        if (idx < XH * 8) {
            int xh = idx >> 3, r = idx & 7, yy = r >> 2, q = r & 3;
            f32x4 mv = map4[((size_t)(b * NX + x0 + xh) * NY + y0 + yy) * 4 + q];
            m_s[yy][q * 4 + 0][xh] = mv.x;
            m_s[yy][q * 4 + 1][xh] = mv.y;
            m_s[yy][q * 4 + 2][xh] = mv.z;
            m_s[yy][q * 4 + 3][xh] = mv.w;
        }
    }
    __syncthreads();

    const size_t out_base = ((size_t)b * CT + C) * PL + (size_t)y0 * NX + x0;
    #pragma unroll
    for (int k = 0; k < 8; ++k) {
        int idx = k * 256 + tid;
        int sl  = idx & 63;
        int cmy = idx >> 6;
        int cm  = cmy >> 1, yy = cmy & 1;
        if (sl < XH4) {
            f32x4 v = *(const f32x4*)&m_s[yy][cm][sl * 4];
            __builtin_nontemporal_store(v,
                (f32x4*)(out + out_base + (size_t)cm * PL
                             + (size_t)yy * NX + sl * 4));
        }
    }
}

// ---------------- fallbacks ----------------
__global__ void zero_vox_region_kernel(float* __restrict__ out) {
    int g = blockIdx.x * 256 + threadIdx.x;
    if (g >= B * C * NY * X4) return;
    int x4   = g % X4;
    int rest = g / X4;
    int y  = rest % NY;
    int bc = rest / NY;
    int c  = bc & (C - 1);
    int b  = bc >> 6;
    *(f32x4*)(out + (((size_t)b * CT + c) * NY + y) * NX + x4 * 4) = (f32x4)0.f;
}

__global__ void scatter_direct_kernel(const float* __restrict__ vox,
                                      const int* __restrict__ coords,
                                      float* __restrict__ out) {
    int p = blockIdx.x;
    int c = threadIdx.x;
    const int4 cd = ((const int4*)coords)[p];
    out[(((size_t)cd.x * CT + c) * NY + cd.z) * NX + cd.w] = vox[(size_t)p * C + c];
}

__global__ void map_only_kernel(const float* __restrict__ map,
                                float* __restrict__ out) {
    int g = blockIdx.x * 256 + threadIdx.x;
    if (g >= B * CMAP * NY * NX) return;
    int x    = g % NX;
    int rest = g / NX;
    int y  = rest % NY;
    int bc = rest / NY;
    int cm = bc & (CMAP - 1);
    int b  = bc >> 4;
    out[((size_t)b * CT + C + cm) * PL + (size_t)y * NX + x] =
        map[((size_t)(b * NX + x) * NY + y) * CMAP + cm];
}

extern "C" void kernel_launch(void* const* d_in, const int* in_sizes, int n_in,
                              void* d_out, int out_size, void* d_ws, size_t ws_size,
                              hipStream_t stream) {
    const float* vox    = (const float*)d_in[0];   // (P, 64) float32
    const int*   coords = (const int*)d_in[1];     // (P, 4) int32
    const float* map    = (const float*)d_in[3];   // (B, NX, NY, CMAP) float32
    float* out = (float*)d_out;                    // (B, 80, NY, NX) float32

    const size_t inv_bytes = (size_t)B * NY * NX * sizeof(int);  // 3.43 MB

    if (ws_size >= OUT_BYTES + inv_bytes) {
        // Measurement round 2: phase-isolating honest probes (to ws),
        // then the real r5 path (to out).
        float* ws_f = (float*)d_ws;
        int*   inv  = (int*)((char*)d_ws + OUT_BYTES);
        (void)hipMemsetAsync(inv, 0xFF, inv_bytes, stream);      // all -1
        scatter_inv_kernel<<<(P + 255) / 256, 256, 0, stream>>>(coords, inv);
        probe_vox_store_kernel<<<dim3(1, NY / 2, B * CQ), 256, 0, stream>>>(ws_f);
        probe_map_read_kernel<<<dim3(2, NY / 2, B), 256, 0, stream>>>(map, ws_f);
        vox_fill_kernel<<<dim3(1, NY / 2, B * CQ), 256, 0, stream>>>(vox, inv, out);
        map_tile_kernel<<<dim3(2, NY / 2, B), 256, 0, stream>>>(map, out);
    } else if (ws_size >= inv_bytes) {
        int* inv = (int*)d_ws;
        (void)hipMemsetAsync(inv, 0xFF, inv_bytes, stream);      // all -1
        scatter_inv_kernel<<<(P + 255) / 256, 256, 0, stream>>>(coords, inv);
        vox_fill_kernel<<<dim3(1, NY / 2, B * CQ), 256, 0, stream>>>(vox, inv, out);
        map_tile_kernel<<<dim3(2, NY / 2, B), 256, 0, stream>>>(map, out);
    } else {
        zero_vox_region_kernel<<<(B * C * NY * X4 + 255) / 256, 256, 0, stream>>>(out);
        scatter_direct_kernel<<<P, 64, 0, stream>>>(vox, coords, out);
        map_only_kernel<<<(B * CMAP * NY * NX + 255) / 256, 256, 0, stream>>>(map, out);
    }
}

// Round 8
// 329.643 us; speedup vs baseline: 2.5839x; 2.5839x over previous
//
#include <hip/hip_runtime.h>
#include <stdint.h>
#include <stddef.h>

typedef __attribute__((ext_vector_type(4))) float f32x4;
typedef __attribute__((ext_vector_type(4))) int   i32x4;

constexpr int B = 4, P = 48000, C = 64, NY = 496, NX = 432, CMAP = 16;
constexpr int CT  = C + CMAP;            // 80 output channels
constexpr int X4  = NX / 4;              // 108 float4 groups per full row
constexpr int CQ  = C / 4;               // 16 channel quads
constexpr size_t PL = (size_t)NY * NX;   // 214,272 channel-plane stride

// map transpose tile geometry (exact: 432 = 48*9, 496 = 16*31)
constexpr int XT   = 48;                 // x per tile
constexpr int YT   = 16;                 // y per tile
constexpr int NRUN = CMAP * YT;          // 256 output runs per tile
constexpr int LSTR = XT + 4;             // 52 words = 13 x 16B: aligned b128,
                                         // uniform super-bank spread

// Pass A: build inverse map cell -> point id (cells unique by construction)
__global__ void scatter_inv_kernel(const int* __restrict__ coords,
                                   int* __restrict__ inv) {
    int p = blockIdx.x * blockDim.x + threadIdx.x;
    if (p >= P) return;
    const int4 cd = ((const int4*)coords)[p];     // (b, 0, y, x)
    inv[(cd.x * NY + cd.z) * NX + cd.w] = p;
}

// Pass B: vox dense fill (r5 structure, unchanged — probe-verified pattern).
__global__ void __launch_bounds__(256) vox_fill_kernel(
        const float* __restrict__ vox, const int* __restrict__ inv,
        float* __restrict__ out) {
    const int x4  = threadIdx.x & 127;
    if (x4 >= X4) return;                          // 20 idle lanes / 128
    const int y   = (blockIdx.y << 1) | (threadIdx.x >> 7);
    const int bcq = blockIdx.z;                    // b*16 + cq
    const int cq  = bcq & (CQ - 1);
    const int b   = bcq >> 4;
    const int c0  = cq * 4;

    i32x4 p4 = ((const i32x4*)inv)[(b * NY + y) * X4 + x4];

    f32x4 r0 = (f32x4)0.f, r1 = (f32x4)0.f, r2 = (f32x4)0.f, r3 = (f32x4)0.f;
    // pids -1 (empty) or >=0; AND keeps sign bit only if ALL empty (~79%)
    if ((p4.x & p4.y & p4.z & p4.w) >= 0) {
        const f32x4* vox4 = (const f32x4*)vox;     // vox row = 16 f32x4
        if (p4.x >= 0) r0 = vox4[(size_t)p4.x * CQ + cq];
        if (p4.y >= 0) r1 = vox4[(size_t)p4.y * CQ + cq];
        if (p4.z >= 0) r2 = vox4[(size_t)p4.z * CQ + cq];
        if (p4.w >= 0) r3 = vox4[(size_t)p4.w * CQ + cq];
    }

    float* ob = out + (((size_t)b * CT + c0) * NY + y) * NX + x4 * 4;
    f32x4 s;
    s.x = r0.x; s.y = r1.x; s.z = r2.x; s.w = r3.x;
    __builtin_nontemporal_store(s, (f32x4*)(ob));
    s.x = r0.y; s.y = r1.y; s.z = r2.y; s.w = r3.y;
    __builtin_nontemporal_store(s, (f32x4*)(ob + PL));
    s.x = r0.z; s.y = r1.z; s.z = r2.z; s.w = r3.z;
    __builtin_nontemporal_store(s, (f32x4*)(ob + 2 * PL));
    s.x = r0.w; s.y = r1.w; s.z = r2.w; s.w = r3.w;
    __builtin_nontemporal_store(s, (f32x4*)(ob + 3 * PL));
}

// Pass C: map transpose with FULLY-COALESCED reads.
// map is (B, NX, NY, CMAP): contiguous along (y, cm). Per tile (48x, 16y):
// read = 48 runs of 1KB contiguous (one full wave-load each, 12 dense iters);
// LDS transpose; write = 256 runs of 192B (3 aligned lines) per (cm,y).
__global__ void __launch_bounds__(256) map_xpose_kernel(
        const float* __restrict__ map, float* __restrict__ out) {
    __shared__ __align__(16) float m_s[NRUN * LSTR];   // 52 KB

    const int tid = threadIdx.x;
    const int x0  = blockIdx.x * XT;              // 0..8 -> 0..384
    const int y0  = blockIdx.y * YT;              // 0..30 -> 0..480
    const int b   = blockIdx.z;

    const f32x4* map4 = (const f32x4*)map;
    // read: idx = xi*64 + qi; wave lanes sweep qi -> 1KB contiguous per x.
    #pragma unroll
    for (int k = 0; k < 12; ++k) {
        int idx = k * 256 + tid;
        int xi  = idx >> 6;                       // 0..47
        int qi  = idx & 63;                       // 0..63: (y,cm) quad
        f32x4 mv = map4[(size_t)(b * NX + x0 + xi) * (NY * CMAP / 4)
                        + (size_t)y0 * (CMAP / 4) + qi];
        int yl  = qi >> 2;                        // 0..15
        int cm0 = (qi & 3) * 4;
        m_s[((cm0 + 0) * YT + yl) * LSTR + xi] = mv.x;
        m_s[((cm0 + 1) * YT + yl) * LSTR + xi] = mv.y;
        m_s[((cm0 + 2) * YT + yl) * LSTR + xi] = mv.z;
        m_s[((cm0 + 3) * YT + yl) * LSTR + xi] = mv.w;
    }
    __syncthreads();

    // write: 256 runs (cm,y) x 12 quads of x; 192B line-aligned bursts.
    const size_t ob = ((size_t)b * CT + C) * PL + (size_t)y0 * NX + x0;
    #pragma unroll
    for (int k = 0; k < 12; ++k) {
        int idx = k * 256 + tid;
        int xq  = idx % 12;
        int run = idx / 12;                       // 0..255
        int cm  = run >> 4, yl = run & 15;
        f32x4 v = *(const f32x4*)&m_s[run * LSTR + xq * 4];
        __builtin_nontemporal_store(v,
            (f32x4*)(out + ob + (size_t)cm * PL + (size_t)yl * NX + xq * 4));
    }
}

// ---------------- fallbacks ----------------
__global__ void zero_vox_region_kernel(float* __restrict__ out) {
    int g = blockIdx.x * 256 + threadIdx.x;
    if (g >= B * C * NY * X4) return;
    int x4   = g % X4;
    int rest = g / X4;
    int y  = rest % NY;
    int bc = rest / NY;
    int c  = bc & (C - 1);
    int b  = bc >> 6;
    *(f32x4*)(out + (((size_t)b * CT + c) * NY + y) * NX + x4 * 4) = (f32x4)0.f;
}

__global__ void scatter_direct_kernel(const float* __restrict__ vox,
                                      const int* __restrict__ coords,
                                      float* __restrict__ out) {
    int p = blockIdx.x;
    int c = threadIdx.x;  // 0..63
    const int4 cd = ((const int4*)coords)[p];
    out[(((size_t)cd.x * CT + c) * NY + cd.z) * NX + cd.w] = vox[(size_t)p * C + c];
}

__global__ void map_only_kernel(const float* __restrict__ map,
                                float* __restrict__ out) {
    int g = blockIdx.x * 256 + threadIdx.x;
    if (g >= B * CMAP * NY * NX) return;
    int x    = g % NX;
    int rest = g / NX;
    int y  = rest % NY;
    int bc = rest / NY;
    int cm = bc & (CMAP - 1);
    int b  = bc >> 4;
    out[((size_t)b * CT + C + cm) * PL + (size_t)y * NX + x] =
        map[((size_t)(b * NX + x) * NY + y) * CMAP + cm];
}

extern "C" void kernel_launch(void* const* d_in, const int* in_sizes, int n_in,
                              void* d_out, int out_size, void* d_ws, size_t ws_size,
                              hipStream_t stream) {
    const float* vox    = (const float*)d_in[0];   // (P, 64) float32
    const int*   coords = (const int*)d_in[1];     // (P, 4) int32
    const float* map    = (const float*)d_in[3];   // (B, NX, NY, CMAP) float32
    float* out = (float*)d_out;                    // (B, 80, NY, NX) float32

    const size_t inv_bytes = (size_t)B * NY * NX * sizeof(int);  // 3.43 MB
    int* inv = (ws_size >= inv_bytes) ? (int*)d_ws : nullptr;

    if (inv) {
        (void)hipMemsetAsync(inv, 0xFF, inv_bytes, stream);      // all -1
        scatter_inv_kernel<<<(P + 255) / 256, 256, 0, stream>>>(coords, inv);
        vox_fill_kernel<<<dim3(1, NY / 2, B * CQ), 256, 0, stream>>>(vox, inv, out);
        map_xpose_kernel<<<dim3(NX / XT, NY / YT, B), 256, 0, stream>>>(map, out);
    } else {
        zero_vox_region_kernel<<<(B * C * NY * X4 + 255) / 256, 256, 0, stream>>>(out);
        scatter_direct_kernel<<<P, 64, 0, stream>>>(vox, coords, out);
        map_only_kernel<<<(B * CMAP * NY * NX + 255) / 256, 256, 0, stream>>>(map, out);
    }
}